// Round 10
// baseline (4615.769 us; speedup 1.0000x reference)
//
#include <hip/hip_runtime.h>

// Problem constants (fixed by the reference file)
#define NODES_C 65536   // N*N, N=256
#define B_C     16
#define E_C     1048576 // NODES*16
#define K_C     5

#define MAXE    2048    // LDS padded-segment cap per 64-node step block (avg ~1250)
#define CAP_D   8192    // fixed padded stride per 256-node bucket (avg padded ~5000)

typedef unsigned long long u64;

__device__ inline unsigned short f2bf(float f) {   // RNE float->bf16
    unsigned u = __float_as_uint(f);
    u += 0x7FFFu + ((u >> 16) & 1u);
    return (unsigned short)(u >> 16);
}

// ---------------------------------------------------------------------------
// Build kernel A: 256-bin histogram of dst>>8
__global__ __launch_bounds__(256) void k_hist(
    const int* __restrict__ dst, int* __restrict__ hist)
{
    __shared__ int h[256];
    int tid = threadIdx.x;
    h[tid] = 0;
    __syncthreads();
    int e0 = blockIdx.x * 1024;
    #pragma unroll
    for (int j = 0; j < 4; ++j)
        atomicAdd(&h[((unsigned)dst[e0 + j * 256 + tid]) >> 8], 1);
    __syncthreads();
    atomicAdd(&hist[tid], h[tid]);
}

// ---------------------------------------------------------------------------
// Build kernel B: exclusive scan of hist256 -> base, fill (raw bucket bases)
__global__ __launch_bounds__(256) void k_scan256(
    const int* __restrict__ hist, int* __restrict__ base, int* __restrict__ fill)
{
    __shared__ int s[256];
    int t = threadIdx.x;
    s[t] = hist[t];
    __syncthreads();
    for (int off = 1; off < 256; off <<= 1) {
        int v = s[t];
        int a = (t >= off) ? s[t - off] : 0;
        __syncthreads();
        s[t] = v + a;
        __syncthreads();
    }
    int ex = (t == 0) ? 0 : s[t - 1];
    base[t] = ex;
    fill[t] = ex;
}

// ---------------------------------------------------------------------------
// Build kernel C: compute w, pack u64 {w_f32 | dst&255 | src16}, bucket by
// dst>>8 into csr (raw bucket-clustered). 256 blocks x 4096 edges.
__global__ __launch_bounds__(256) void k_bucket(
    const int* __restrict__ src, const int* __restrict__ dst,
    const float* __restrict__ dist, const float* __restrict__ coeffs,
    int* __restrict__ fill, u64* __restrict__ csr)
{
    __shared__ int hist[256];
    __shared__ int scan[256];
    __shared__ int exs[256];
    __shared__ int gpos[256];
    __shared__ int lfill[256];
    __shared__ u64 stage[4096];

    int tid = threadIdx.x;
    hist[tid] = 0;
    __syncthreads();

    float c0 = coeffs[0], c1 = coeffs[1], c2 = coeffs[2], c3 = coeffs[3], c4 = coeffs[4];
    int e0 = blockIdx.x * 4096;
    u64 pk[16];
    int bk[16];
    #pragma unroll
    for (int j = 0; j < 16; ++j) {
        int e = e0 + j * 256 + tid;
        unsigned s = (unsigned)src[e];
        unsigned d = (unsigned)dst[e];
        const float* dd = dist + (size_t)e * K_C;
        float wv = dd[0]*c0 + dd[1]*c1 + dd[2]*c2 + dd[3]*c3 + dd[4]*c4;
        pk[j] = ((u64)__float_as_uint(wv) << 32) | ((d & 255u) << 16) | s;
        bk[j] = (int)(d >> 8);
        atomicAdd(&hist[bk[j]], 1);
    }
    __syncthreads();

    scan[tid] = hist[tid];
    __syncthreads();
    for (int off = 1; off < 256; off <<= 1) {
        int v = scan[tid];
        int a = (tid >= off) ? scan[tid - off] : 0;
        __syncthreads();
        scan[tid] = v + a;
        __syncthreads();
    }
    exs[tid]   = scan[tid] - hist[tid];
    gpos[tid]  = atomicAdd(&fill[tid], hist[tid]);
    lfill[tid] = 0;
    __syncthreads();

    #pragma unroll
    for (int j = 0; j < 16; ++j) {
        int b = bk[j];
        int p = exs[b] + atomicAdd(&lfill[b], 1);
        stage[p] = pk[j];
    }
    __syncthreads();

    int c = hist[tid], g = gpos[tid], lb = exs[tid];
    for (int i = 0; i < c; ++i) csr[g + i] = stage[lb + i];
}

// ---------------------------------------------------------------------------
// Build kernel D: one block per bucket. Counting-sort by dst&255 with rows
// PADDED to multiples of 8 (zero entries), emitted as u32 {bf16 w | u16 src}
// at the bucket's FIXED stride B0 = b*CAP_D. Emits padded row_start.
__global__ __launch_bounds__(256) void k_sortb(
    const int* __restrict__ base, const int* __restrict__ hist,
    const u64* __restrict__ csr, unsigned* __restrict__ csr2,
    int* __restrict__ row_start)
{
    __shared__ unsigned stage[CAP_D];
    __shared__ int h[256];
    __shared__ int sc[256];
    __shared__ int ex[256];
    __shared__ int lf[256];

    int b = blockIdx.x, tid = threadIdx.x;
    int b0 = base[b];
    int len = hist[b];
    int B0 = b * CAP_D;

    h[tid] = 0;
    for (int i = tid; i < CAP_D; i += 256) stage[i] = 0;   // pad entries: w=0,src=0
    __syncthreads();
    for (int i = tid; i < len; i += 256)
        atomicAdd(&h[(int)((csr[b0 + i] >> 16) & 255u)], 1);
    __syncthreads();

    int hp = (h[tid] + 7) & ~7;              // padded row length
    sc[tid] = hp;
    __syncthreads();
    for (int off = 1; off < 256; off <<= 1) {
        int v = sc[tid];
        int a = (tid >= off) ? sc[tid - off] : 0;
        __syncthreads();
        sc[tid] = v + a;
        __syncthreads();
    }
    ex[tid] = sc[tid] - hp;                  // padded exclusive base
    row_start[b * 256 + tid] = B0 + ex[tid];
    lf[tid] = 0;
    __syncthreads();

    for (int i = tid; i < len; i += 256) {
        u64 m = csr[b0 + i];
        int dl = (int)((m >> 16) & 255u);
        int p = ex[dl] + atomicAdd(&lf[dl], 1);
        unsigned wbf = ((unsigned)f2bf(__uint_as_float((unsigned)(m >> 32)))) << 16;
        stage[p] = wbf | (unsigned)(m & 0xFFFFu);
    }
    __syncthreads();
    int plen = sc[255];
    for (int i = tid; i < plen; i += 256) csr2[B0 + i] = stage[i];
    if (b == 255 && tid == 255) row_start[NODES_C] = B0 + plen;
}

// ---------------------------------------------------------------------------
// Kernel: init node-major f32 state + two bf16 half-mirrors [n][8]
__global__ __launch_bounds__(256) void k_init(
    const float* __restrict__ x_in, float* __restrict__ xf,
    unsigned short* __restrict__ mA, unsigned short* __restrict__ mB)
{
    int tid = blockIdx.x * 256 + threadIdx.x;   // tid = b*N + n
    int b = tid >> 16;
    int n = tid & 0xFFFF;
    float v = x_in[tid];
    xf[((size_t)n << 4) + b] = v;
    unsigned short* m = (b < 8) ? mA : mB;
    m[((size_t)n << 3) + (b & 7)] = f2bf(v);
}

// ---------------------------------------------------------------------------
// Step kernel, batch-split: blocks 0..1023 -> batches 0-7 (mirror A),
// blocks 1024..2047 -> batches 8-15 (mirror B). Block = 64 nodes,
// thread = (node, batch-pair-within-half). Rows padded to x8: no tail mask.
__global__ __launch_bounds__(256, 8) void k_step(
    const int* __restrict__ row_start, const unsigned* __restrict__ csr2,
    float* __restrict__ xf,
    const unsigned short* __restrict__ mAc, unsigned short* __restrict__ mAn,
    const unsigned short* __restrict__ mBc, unsigned short* __restrict__ mBn,
    float* __restrict__ out, const float* __restrict__ dt_p,
    size_t TN, int tstep)
{
    __shared__ unsigned meta[MAXE];
    __shared__ int rows[65];
    __shared__ float tile[64][9];

    int tid  = threadIdx.x;
    int half = blockIdx.x >> 10;        // 0 or 1
    int gb   = blockIdx.x & 1023;
    int n0   = gb * 64;

    const unsigned short* mc = half ? mBc : mAc;
    unsigned short*       mn = half ? mBn : mAn;

    if (tid < 65) rows[tid] = row_start[n0 + tid];
    __syncthreads();
    int seg0   = rows[0];
    int segLen = rows[64] - seg0;
    bool lds_ok = (segLen <= MAXE);
    if (lds_ok)
        for (int i = tid; i < segLen; i += 256) meta[i] = csr2[seg0 + i];
    __syncthreads();

    int ln = tid >> 2;            // local node 0..63
    int oc = tid & 3;             // batch pair within half
    int n  = n0 + ln;
    int r0 = rows[ln]     - seg0;
    int r1 = rows[ln + 1] - seg0;

    float a0 = 0.f, a1 = 0.f;
    const unsigned short* xq = mc + (oc << 1);

    if (lds_ok) {
        for (int i = r0; i < r1; i += 8) {
            unsigned mm[8];
            unsigned rv[8];
            #pragma unroll
            for (int j = 0; j < 8; ++j) mm[j] = meta[i + j];
            #pragma unroll
            for (int j = 0; j < 8; ++j)
                rv[j] = *(const unsigned*)(xq + ((size_t)(mm[j] & 0xFFFFu) << 3));
            #pragma unroll
            for (int j = 0; j < 8; ++j) {
                float w = __uint_as_float(mm[j] & 0xFFFF0000u);
                a0 = fmaf(w, __uint_as_float(rv[j] << 16), a0);
                a1 = fmaf(w, __uint_as_float(rv[j] & 0xFFFF0000u), a1);
            }
        }
    } else {
        for (int i = r0; i < r1; i += 8) {
            unsigned mm[8];
            unsigned rv[8];
            #pragma unroll
            for (int j = 0; j < 8; ++j) mm[j] = csr2[seg0 + i + j];
            #pragma unroll
            for (int j = 0; j < 8; ++j)
                rv[j] = *(const unsigned*)(xq + ((size_t)(mm[j] & 0xFFFFu) << 3));
            #pragma unroll
            for (int j = 0; j < 8; ++j) {
                float w = __uint_as_float(mm[j] & 0xFFFF0000u);
                a0 = fmaf(w, __uint_as_float(rv[j] << 16), a0);
                a1 = fmaf(w, __uint_as_float(rv[j] & 0xFFFF0000u), a1);
            }
        }
    }

    float dt = dt_p[0];
    size_t own = ((size_t)n << 4) + (half << 3) + (oc << 1);
    float2 xo = *(const float2*)(xf + own);
    xo.x = fmaf(dt, a0, xo.x);
    xo.y = fmaf(dt, a1, xo.y);
    *(float2*)(xf + own) = xo;

    unsigned pk = ((unsigned)f2bf(xo.x)) | (((unsigned)f2bf(xo.y)) << 16);
    *(unsigned*)(mn + ((size_t)n << 3) + (oc << 1)) = pk;

    // LDS transpose: 64 nodes x 8 batches -> coalesced out writes
    int c0 = oc << 1;
    tile[ln][c0 + 0] = xo.x;
    tile[ln][c0 + 1] = xo.y;
    __syncthreads();
    int wb = tid >> 5;                // local batch 0..7
    int wn = (tid & 31) << 1;         // local node 0,2,..,62
    float2 ov;
    ov.x = tile[wn + 0][wb];
    ov.y = tile[wn + 1][wb];
    *(float2*)(out + (size_t)(half * 8 + wb) * TN + (size_t)tstep * NODES_C + n0 + wn) = ov;
}

// ---------------------------------------------------------------------------
extern "C" void kernel_launch(void* const* d_in, const int* in_sizes, int n_in,
                              void* d_out, int out_size, void* d_ws, size_t ws_size,
                              hipStream_t stream)
{
    const float* x_in   = (const float*)d_in[0];
    // d_in[1] = points (unused by the reference computation)
    const int*   eidx   = (const int*)d_in[2];
    const float* dt_p   = (const float*)d_in[3];
    // d_in[4] = num_blocks (T derived from out_size instead)
    const float* dist   = (const float*)d_in[5];
    const float* coeffs = (const float*)d_in[6];

    const int* src = eidx;          // edge_index[0]
    const int* dst = eidx + E_C;    // edge_index[1]
    float* out = (float*)d_out;

    // workspace layout (~25 MB)
    char* ws = (char*)d_ws;
    int*      row_start = (int*)(ws + 0);                  // 256 KB + 4
    int*      hist256   = (int*)(ws + (512u << 10));       // 1 KB
    int*      base256   = (int*)(ws + (516u << 10));       // 1 KB
    int*      fill256   = (int*)(ws + (520u << 10));       // 1 KB
    u64*      csr       = (u64*)(ws + (1u  << 20));        // 8 MB (raw bucketed)
    unsigned* csr2      = (unsigned*)(ws + (9u << 20));    // 8 MB (padded u32)
    float*    xf        = (float*)(ws + (17u << 20));      // 4 MB f32 state
    unsigned short* mA0 = (unsigned short*)(ws + (21u << 20)); // 1 MB
    unsigned short* mA1 = (unsigned short*)(ws + (22u << 20)); // 1 MB
    unsigned short* mB0 = (unsigned short*)(ws + (23u << 20)); // 1 MB
    unsigned short* mB1 = (unsigned short*)(ws + (24u << 20)); // 1 MB

    int T = out_size / (B_C * NODES_C);          // = 20
    size_t TN = (size_t)T * NODES_C;

    hipMemsetAsync(hist256, 0, 256 * sizeof(int), stream);
    k_hist   <<<E_C / 1024, 256, 0, stream>>>(dst, hist256);
    k_scan256<<<1, 256, 0, stream>>>(hist256, base256, fill256);
    k_bucket <<<E_C / 4096, 256, 0, stream>>>(src, dst, dist, coeffs, fill256, csr);
    k_sortb  <<<256, 256, 0, stream>>>(base256, hist256, csr, csr2, row_start);
    k_init   <<<(NODES_C * B_C) / 256, 256, 0, stream>>>(x_in, xf, mA0, mB0);

    unsigned short* mAs[2] = { mA0, mA1 };
    unsigned short* mBs[2] = { mB0, mB1 };
    for (int t = 0; t < T; ++t) {
        k_step<<<2048, 256, 0, stream>>>(
            row_start, csr2, xf,
            mAs[t & 1], mAs[(t + 1) & 1], mBs[t & 1], mBs[(t + 1) & 1],
            out, dt_p, TN, t);
    }
}

// Round 11
// 355.599 us; speedup vs baseline: 12.9802x; 12.9802x over previous
//
#include <hip/hip_runtime.h>

// Problem constants (fixed by the reference file)
#define NODES_C 65536   // N*N, N=256
#define B_C     16
#define E_C     1048576 // NODES*16
#define K_C     5

#define MAXE    2048    // LDS padded-segment cap per 64-node step block (avg ~1280)
#define CAP_D   8192    // fixed padded stride per 256-node bucket (avg padded ~5100)

typedef unsigned long long u64;

__device__ inline unsigned short f2bf(float f) {   // RNE float->bf16
    unsigned u = __float_as_uint(f);
    u += 0x7FFFu + ((u >> 16) & 1u);
    return (unsigned short)(u >> 16);
}

// ---------------------------------------------------------------------------
// Build kernel A: 256-bin histogram of dst>>8
__global__ __launch_bounds__(256) void k_hist(
    const int* __restrict__ dst, int* __restrict__ hist)
{
    __shared__ int h[256];
    int tid = threadIdx.x;
    h[tid] = 0;
    __syncthreads();
    int e0 = blockIdx.x * 1024;
    #pragma unroll
    for (int j = 0; j < 4; ++j)
        atomicAdd(&h[((unsigned)dst[e0 + j * 256 + tid]) >> 8], 1);
    __syncthreads();
    atomicAdd(&hist[tid], h[tid]);
}

// ---------------------------------------------------------------------------
// Build kernel B: exclusive scan of hist256 -> base, fill (raw bucket bases)
__global__ __launch_bounds__(256) void k_scan256(
    const int* __restrict__ hist, int* __restrict__ base, int* __restrict__ fill)
{
    __shared__ int s[256];
    int t = threadIdx.x;
    s[t] = hist[t];
    __syncthreads();
    for (int off = 1; off < 256; off <<= 1) {
        int v = s[t];
        int a = (t >= off) ? s[t - off] : 0;
        __syncthreads();
        s[t] = v + a;
        __syncthreads();
    }
    int ex = (t == 0) ? 0 : s[t - 1];
    base[t] = ex;
    fill[t] = ex;
}

// ---------------------------------------------------------------------------
// Build kernel C: compute w, pack u64 {w_f32 | dst&255 | src16}, bucket by
// dst>>8 into csr (raw bucket-clustered). 256 blocks x 4096 edges.
__global__ __launch_bounds__(256) void k_bucket(
    const int* __restrict__ src, const int* __restrict__ dst,
    const float* __restrict__ dist, const float* __restrict__ coeffs,
    int* __restrict__ fill, u64* __restrict__ csr)
{
    __shared__ int hist[256];
    __shared__ int scan[256];
    __shared__ int exs[256];
    __shared__ int gpos[256];
    __shared__ int lfill[256];
    __shared__ u64 stage[4096];

    int tid = threadIdx.x;
    hist[tid] = 0;
    __syncthreads();

    float c0 = coeffs[0], c1 = coeffs[1], c2 = coeffs[2], c3 = coeffs[3], c4 = coeffs[4];
    int e0 = blockIdx.x * 4096;
    u64 pk[16];
    int bk[16];
    #pragma unroll
    for (int j = 0; j < 16; ++j) {
        int e = e0 + j * 256 + tid;
        unsigned s = (unsigned)src[e];
        unsigned d = (unsigned)dst[e];
        const float* dd = dist + (size_t)e * K_C;
        float wv = dd[0]*c0 + dd[1]*c1 + dd[2]*c2 + dd[3]*c3 + dd[4]*c4;
        pk[j] = ((u64)__float_as_uint(wv) << 32) | ((d & 255u) << 16) | s;
        bk[j] = (int)(d >> 8);
        atomicAdd(&hist[bk[j]], 1);
    }
    __syncthreads();

    scan[tid] = hist[tid];
    __syncthreads();
    for (int off = 1; off < 256; off <<= 1) {
        int v = scan[tid];
        int a = (tid >= off) ? scan[tid - off] : 0;
        __syncthreads();
        scan[tid] = v + a;
        __syncthreads();
    }
    exs[tid]   = scan[tid] - hist[tid];
    gpos[tid]  = atomicAdd(&fill[tid], hist[tid]);
    lfill[tid] = 0;
    __syncthreads();

    #pragma unroll
    for (int j = 0; j < 16; ++j) {
        int b = bk[j];
        int p = exs[b] + atomicAdd(&lfill[b], 1);
        stage[p] = pk[j];
    }
    __syncthreads();

    int c = hist[tid], g = gpos[tid], lb = exs[tid];
    for (int i = 0; i < c; ++i) csr[g + i] = stage[lb + i];
}

// ---------------------------------------------------------------------------
// Build kernel D: one block per bucket. Counting-sort by dst&255 with rows
// PADDED to multiples of 8 (zero entries), emitted as u32 {bf16 w | u16 src}
// at the bucket's FIXED stride B0 = b*CAP_D. Emits row_start AND row_end
// (row_end avoids swallowing the bucket's pad-tail gap at block boundaries).
__global__ __launch_bounds__(256) void k_sortb(
    const int* __restrict__ base, const int* __restrict__ hist,
    const u64* __restrict__ csr, unsigned* __restrict__ csr2,
    int* __restrict__ row_start, int* __restrict__ row_end)
{
    __shared__ unsigned stage[CAP_D];
    __shared__ int h[256];
    __shared__ int sc[256];
    __shared__ int ex[256];
    __shared__ int lf[256];

    int b = blockIdx.x, tid = threadIdx.x;
    int b0 = base[b];
    int len = hist[b];
    int B0 = b * CAP_D;

    h[tid] = 0;
    for (int i = tid; i < CAP_D; i += 256) stage[i] = 0;   // pad entries: w=0,src=0
    __syncthreads();
    for (int i = tid; i < len; i += 256)
        atomicAdd(&h[(int)((csr[b0 + i] >> 16) & 255u)], 1);
    __syncthreads();

    int hp = (h[tid] + 7) & ~7;              // padded row length
    sc[tid] = hp;
    __syncthreads();
    for (int off = 1; off < 256; off <<= 1) {
        int v = sc[tid];
        int a = (tid >= off) ? sc[tid - off] : 0;
        __syncthreads();
        sc[tid] = v + a;
        __syncthreads();
    }
    ex[tid] = sc[tid] - hp;                  // padded exclusive base
    row_start[b * 256 + tid] = B0 + ex[tid];
    row_end  [b * 256 + tid] = B0 + ex[tid] + hp;
    lf[tid] = 0;
    __syncthreads();

    for (int i = tid; i < len; i += 256) {
        u64 m = csr[b0 + i];
        int dl = (int)((m >> 16) & 255u);
        int p = ex[dl] + atomicAdd(&lf[dl], 1);
        unsigned wbf = ((unsigned)f2bf(__uint_as_float((unsigned)(m >> 32)))) << 16;
        stage[p] = wbf | (unsigned)(m & 0xFFFFu);
    }
    __syncthreads();
    int plen = sc[255];
    for (int i = tid; i < plen; i += 256) csr2[B0 + i] = stage[i];
}

// ---------------------------------------------------------------------------
// Kernel: init node-major f32 state + two bf16 half-mirrors [n][8]
__global__ __launch_bounds__(256) void k_init(
    const float* __restrict__ x_in, float* __restrict__ xf,
    unsigned short* __restrict__ mA, unsigned short* __restrict__ mB)
{
    int tid = blockIdx.x * 256 + threadIdx.x;   // tid = b*N + n
    int b = tid >> 16;
    int n = tid & 0xFFFF;
    float v = x_in[tid];
    xf[((size_t)n << 4) + b] = v;
    unsigned short* m = (b < 8) ? mA : mB;
    m[((size_t)n << 3) + (b & 7)] = f2bf(v);
}

// ---------------------------------------------------------------------------
// Step kernel, batch-split: blocks 0..1023 -> batches 0-7 (mirror A),
// blocks 1024..2047 -> batches 8-15 (mirror B). Block = 64 nodes,
// thread = (node, batch-pair-within-half). Rows padded to x8: no tail mask.
// Blocks lie wholly inside one bucket; rows within a bucket are contiguous,
// so the block segment is [rs[n0], re[n0+63]) with no pad-gap.
__global__ __launch_bounds__(256, 8) void k_step(
    const int* __restrict__ row_start, const int* __restrict__ row_end,
    const unsigned* __restrict__ csr2, float* __restrict__ xf,
    const unsigned short* __restrict__ mAc, unsigned short* __restrict__ mAn,
    const unsigned short* __restrict__ mBc, unsigned short* __restrict__ mBn,
    float* __restrict__ out, const float* __restrict__ dt_p,
    size_t TN, int tstep)
{
    __shared__ unsigned meta[MAXE];
    __shared__ int rows[65];
    __shared__ float tile[64][9];

    int tid  = threadIdx.x;
    int half = blockIdx.x >> 10;        // 0 or 1
    int gb   = blockIdx.x & 1023;
    int n0   = gb * 64;

    const unsigned short* mc = half ? mBc : mAc;
    unsigned short*       mn = half ? mBn : mAn;

    if (tid < 64) rows[tid] = row_start[n0 + tid];
    if (tid == 64) rows[64] = row_end[n0 + 63];
    __syncthreads();
    int seg0   = rows[0];
    int segLen = rows[64] - seg0;
    bool lds_ok = (segLen <= MAXE);
    if (lds_ok)
        for (int i = tid; i < segLen; i += 256) meta[i] = csr2[seg0 + i];
    __syncthreads();

    int ln = tid >> 2;            // local node 0..63
    int oc = tid & 3;             // batch pair within half
    int n  = n0 + ln;
    int r0 = rows[ln] - seg0;
    int r1 = ((ln == 63) ? rows[64] : rows[ln + 1]) - seg0;

    float a0 = 0.f, a1 = 0.f;
    const unsigned short* xq = mc + (oc << 1);

    if (lds_ok) {
        for (int i = r0; i < r1; i += 8) {
            unsigned mm[8];
            unsigned rv[8];
            #pragma unroll
            for (int j = 0; j < 8; ++j) mm[j] = meta[i + j];
            #pragma unroll
            for (int j = 0; j < 8; ++j)
                rv[j] = *(const unsigned*)(xq + ((size_t)(mm[j] & 0xFFFFu) << 3));
            #pragma unroll
            for (int j = 0; j < 8; ++j) {
                float w = __uint_as_float(mm[j] & 0xFFFF0000u);
                a0 = fmaf(w, __uint_as_float(rv[j] << 16), a0);
                a1 = fmaf(w, __uint_as_float(rv[j] & 0xFFFF0000u), a1);
            }
        }
    } else {
        for (int i = r0; i < r1; i += 8) {
            unsigned mm[8];
            unsigned rv[8];
            #pragma unroll
            for (int j = 0; j < 8; ++j) mm[j] = csr2[seg0 + i + j];
            #pragma unroll
            for (int j = 0; j < 8; ++j)
                rv[j] = *(const unsigned*)(xq + ((size_t)(mm[j] & 0xFFFFu) << 3));
            #pragma unroll
            for (int j = 0; j < 8; ++j) {
                float w = __uint_as_float(mm[j] & 0xFFFF0000u);
                a0 = fmaf(w, __uint_as_float(rv[j] << 16), a0);
                a1 = fmaf(w, __uint_as_float(rv[j] & 0xFFFF0000u), a1);
            }
        }
    }

    float dt = dt_p[0];
    size_t own = ((size_t)n << 4) + (half << 3) + (oc << 1);
    float2 xo = *(const float2*)(xf + own);
    xo.x = fmaf(dt, a0, xo.x);
    xo.y = fmaf(dt, a1, xo.y);
    *(float2*)(xf + own) = xo;

    unsigned pk = ((unsigned)f2bf(xo.x)) | (((unsigned)f2bf(xo.y)) << 16);
    *(unsigned*)(mn + ((size_t)n << 3) + (oc << 1)) = pk;

    // LDS transpose: 64 nodes x 8 batches -> coalesced out writes
    int c0 = oc << 1;
    tile[ln][c0 + 0] = xo.x;
    tile[ln][c0 + 1] = xo.y;
    __syncthreads();
    int wb = tid >> 5;                // local batch 0..7
    int wn = (tid & 31) << 1;         // local node 0,2,..,62
    float2 ov;
    ov.x = tile[wn + 0][wb];
    ov.y = tile[wn + 1][wb];
    *(float2*)(out + (size_t)(half * 8 + wb) * TN + (size_t)tstep * NODES_C + n0 + wn) = ov;
}

// ---------------------------------------------------------------------------
extern "C" void kernel_launch(void* const* d_in, const int* in_sizes, int n_in,
                              void* d_out, int out_size, void* d_ws, size_t ws_size,
                              hipStream_t stream)
{
    const float* x_in   = (const float*)d_in[0];
    // d_in[1] = points (unused by the reference computation)
    const int*   eidx   = (const int*)d_in[2];
    const float* dt_p   = (const float*)d_in[3];
    // d_in[4] = num_blocks (T derived from out_size instead)
    const float* dist   = (const float*)d_in[5];
    const float* coeffs = (const float*)d_in[6];

    const int* src = eidx;          // edge_index[0]
    const int* dst = eidx + E_C;    // edge_index[1]
    float* out = (float*)d_out;

    // workspace layout (~25 MB)
    char* ws = (char*)d_ws;
    int*      row_start = (int*)(ws + 0);                  // 256 KB
    int*      row_end   = (int*)(ws + (256u << 10));       // 256 KB
    int*      hist256   = (int*)(ws + (512u << 10));       // 1 KB
    int*      base256   = (int*)(ws + (516u << 10));       // 1 KB
    int*      fill256   = (int*)(ws + (520u << 10));       // 1 KB
    u64*      csr       = (u64*)(ws + (1u  << 20));        // 8 MB (raw bucketed)
    unsigned* csr2      = (unsigned*)(ws + (9u << 20));    // 8 MB (padded u32)
    float*    xf        = (float*)(ws + (17u << 20));      // 4 MB f32 state
    unsigned short* mA0 = (unsigned short*)(ws + (21u << 20)); // 1 MB
    unsigned short* mA1 = (unsigned short*)(ws + (22u << 20)); // 1 MB
    unsigned short* mB0 = (unsigned short*)(ws + (23u << 20)); // 1 MB
    unsigned short* mB1 = (unsigned short*)(ws + (24u << 20)); // 1 MB

    int T = out_size / (B_C * NODES_C);          // = 20
    size_t TN = (size_t)T * NODES_C;

    hipMemsetAsync(hist256, 0, 256 * sizeof(int), stream);
    k_hist   <<<E_C / 1024, 256, 0, stream>>>(dst, hist256);
    k_scan256<<<1, 256, 0, stream>>>(hist256, base256, fill256);
    k_bucket <<<E_C / 4096, 256, 0, stream>>>(src, dst, dist, coeffs, fill256, csr);
    k_sortb  <<<256, 256, 0, stream>>>(base256, hist256, csr, csr2, row_start, row_end);
    k_init   <<<(NODES_C * B_C) / 256, 256, 0, stream>>>(x_in, xf, mA0, mB0);

    unsigned short* mAs[2] = { mA0, mA1 };
    unsigned short* mBs[2] = { mB0, mB1 };
    for (int t = 0; t < T; ++t) {
        k_step<<<2048, 256, 0, stream>>>(
            row_start, row_end, csr2, xf,
            mAs[t & 1], mAs[(t + 1) & 1], mBs[t & 1], mBs[(t + 1) & 1],
            out, dt_p, TN, t);
    }
}

// Round 12
// 281.168 us; speedup vs baseline: 16.4164x; 1.2647x over previous
//
#include <hip/hip_runtime.h>

// Problem constants (fixed by the reference file)
#define NODES_C 65536   // N*N, N=256
#define B_C     16
#define E_C     1048576 // NODES*16
#define K_C     5

#define MAXE    1024    // LDS padded-segment cap per 32-node step block (avg ~624, ~17 sigma)
#define CAP_D   8192    // fixed padded stride per 256-node bucket (avg padded ~5000)

typedef unsigned long long u64;

__device__ inline unsigned short f2bf(float f) {   // RNE float->bf16
    unsigned u = __float_as_uint(f);
    u += 0x7FFFu + ((u >> 16) & 1u);
    return (unsigned short)(u >> 16);
}

// ---------------------------------------------------------------------------
// Build kernel A: 256-bin histogram of dst>>8
__global__ __launch_bounds__(256) void k_hist(
    const int* __restrict__ dst, int* __restrict__ hist)
{
    __shared__ int h[256];
    int tid = threadIdx.x;
    h[tid] = 0;
    __syncthreads();
    int e0 = blockIdx.x * 1024;
    #pragma unroll
    for (int j = 0; j < 4; ++j)
        atomicAdd(&h[((unsigned)dst[e0 + j * 256 + tid]) >> 8], 1);
    __syncthreads();
    atomicAdd(&hist[tid], h[tid]);
}

// ---------------------------------------------------------------------------
// Build kernel B: exclusive scan of hist256 -> base, fill (raw bucket bases)
__global__ __launch_bounds__(256) void k_scan256(
    const int* __restrict__ hist, int* __restrict__ base, int* __restrict__ fill)
{
    __shared__ int s[256];
    int t = threadIdx.x;
    s[t] = hist[t];
    __syncthreads();
    for (int off = 1; off < 256; off <<= 1) {
        int v = s[t];
        int a = (t >= off) ? s[t - off] : 0;
        __syncthreads();
        s[t] = v + a;
        __syncthreads();
    }
    int ex = (t == 0) ? 0 : s[t - 1];
    base[t] = ex;
    fill[t] = ex;
}

// ---------------------------------------------------------------------------
// Build kernel C: compute w, pack u64 {w_f32 | dst&255 | src16}, bucket by
// dst>>8 into csr (raw bucket-clustered). 256 blocks x 4096 edges.
__global__ __launch_bounds__(256) void k_bucket(
    const int* __restrict__ src, const int* __restrict__ dst,
    const float* __restrict__ dist, const float* __restrict__ coeffs,
    int* __restrict__ fill, u64* __restrict__ csr)
{
    __shared__ int hist[256];
    __shared__ int scan[256];
    __shared__ int exs[256];
    __shared__ int gpos[256];
    __shared__ int lfill[256];
    __shared__ u64 stage[4096];

    int tid = threadIdx.x;
    hist[tid] = 0;
    __syncthreads();

    float c0 = coeffs[0], c1 = coeffs[1], c2 = coeffs[2], c3 = coeffs[3], c4 = coeffs[4];
    int e0 = blockIdx.x * 4096;
    u64 pk[16];
    int bk[16];
    #pragma unroll
    for (int j = 0; j < 16; ++j) {
        int e = e0 + j * 256 + tid;
        unsigned s = (unsigned)src[e];
        unsigned d = (unsigned)dst[e];
        const float* dd = dist + (size_t)e * K_C;
        float wv = dd[0]*c0 + dd[1]*c1 + dd[2]*c2 + dd[3]*c3 + dd[4]*c4;
        pk[j] = ((u64)__float_as_uint(wv) << 32) | ((d & 255u) << 16) | s;
        bk[j] = (int)(d >> 8);
        atomicAdd(&hist[bk[j]], 1);
    }
    __syncthreads();

    scan[tid] = hist[tid];
    __syncthreads();
    for (int off = 1; off < 256; off <<= 1) {
        int v = scan[tid];
        int a = (tid >= off) ? scan[tid - off] : 0;
        __syncthreads();
        scan[tid] = v + a;
        __syncthreads();
    }
    exs[tid]   = scan[tid] - hist[tid];
    gpos[tid]  = atomicAdd(&fill[tid], hist[tid]);
    lfill[tid] = 0;
    __syncthreads();

    #pragma unroll
    for (int j = 0; j < 16; ++j) {
        int b = bk[j];
        int p = exs[b] + atomicAdd(&lfill[b], 1);
        stage[p] = pk[j];
    }
    __syncthreads();

    int c = hist[tid], g = gpos[tid], lb = exs[tid];
    for (int i = 0; i < c; ++i) csr[g + i] = stage[lb + i];
}

// ---------------------------------------------------------------------------
// Build kernel D: one block per bucket. Counting-sort by dst&255 with rows
// PADDED to multiples of 8 (zero entries: w=0, src=0), emitted as u32
// {bf16 w | u16 src} at the bucket's FIXED base B0 = b*CAP_D.
// Emits row_start AND row_end (row_end avoids swallowing the pad-tail gap).
__global__ __launch_bounds__(256) void k_sortb(
    const int* __restrict__ base, const int* __restrict__ hist,
    const u64* __restrict__ csr, unsigned* __restrict__ csr2,
    int* __restrict__ row_start, int* __restrict__ row_end)
{
    __shared__ unsigned stage[CAP_D];
    __shared__ int h[256];
    __shared__ int sc[256];
    __shared__ int ex[256];
    __shared__ int lf[256];

    int b = blockIdx.x, tid = threadIdx.x;
    int b0 = base[b];
    int len = hist[b];
    int B0 = b * CAP_D;

    h[tid] = 0;
    for (int i = tid; i < CAP_D; i += 256) stage[i] = 0;   // pad entries
    __syncthreads();
    for (int i = tid; i < len; i += 256)
        atomicAdd(&h[(int)((csr[b0 + i] >> 16) & 255u)], 1);
    __syncthreads();

    int hp = (h[tid] + 7) & ~7;              // padded row length
    sc[tid] = hp;
    __syncthreads();
    for (int off = 1; off < 256; off <<= 1) {
        int v = sc[tid];
        int a = (tid >= off) ? sc[tid - off] : 0;
        __syncthreads();
        sc[tid] = v + a;
        __syncthreads();
    }
    ex[tid] = sc[tid] - hp;                  // padded exclusive base
    row_start[b * 256 + tid] = B0 + ex[tid];
    row_end  [b * 256 + tid] = B0 + ex[tid] + hp;
    lf[tid] = 0;
    __syncthreads();

    for (int i = tid; i < len; i += 256) {
        u64 m = csr[b0 + i];
        int dl = (int)((m >> 16) & 255u);
        int p = ex[dl] + atomicAdd(&lf[dl], 1);
        unsigned wbf = ((unsigned)f2bf(__uint_as_float((unsigned)(m >> 32)))) << 16;
        stage[p] = wbf | (unsigned)(m & 0xFFFFu);
    }
    __syncthreads();
    int plen = sc[255];
    for (int i = tid; i < plen; i += 256) csr2[B0 + i] = stage[i];
}

// ---------------------------------------------------------------------------
// Kernel: init node-major f32 state + full bf16 mirror [n][16]
__global__ __launch_bounds__(256) void k_init(
    const float* __restrict__ x_in, float* __restrict__ xf,
    unsigned short* __restrict__ xb)
{
    int tid = blockIdx.x * 256 + threadIdx.x;   // tid = b*N + n
    int b = tid >> 16;
    int n = tid & 0xFFFF;
    float v = x_in[tid];
    xf[((size_t)n << 4) + b] = v;
    xb[((size_t)n << 4) + b] = f2bf(v);
}

// ---------------------------------------------------------------------------
// Step kernel (r9 shape + padded 4B meta): 32-node blocks, 8 lanes/node
// (each lane owns a batch pair -> 8 lanes x 4B = one 32B request per edge),
// 2048 blocks = 32 waves/CU. Rows padded to x8: no tail masking.
// Blocks lie wholly inside one bucket, so segment = [rs[n0], re[n0+31]).
__global__ __launch_bounds__(256, 8) void k_step(
    const int* __restrict__ row_start, const int* __restrict__ row_end,
    const unsigned* __restrict__ csr2, float* __restrict__ xf,
    const unsigned short* __restrict__ xbc, unsigned short* __restrict__ xbn,
    float* __restrict__ out, const float* __restrict__ dt_p,
    size_t TN, int tstep)
{
    __shared__ unsigned meta[MAXE];
    __shared__ int rows[33];
    __shared__ float tile[32][17];

    int tid = threadIdx.x;
    int n0  = blockIdx.x * 32;

    if (tid < 32) rows[tid] = row_start[n0 + tid];
    if (tid == 32) rows[32] = row_end[n0 + 31];
    __syncthreads();
    int seg0   = rows[0];
    int segLen = rows[32] - seg0;
    bool lds_ok = (segLen <= MAXE);
    if (lds_ok)
        for (int i = tid; i < segLen; i += 256) meta[i] = csr2[seg0 + i];
    __syncthreads();

    int ln = tid >> 3;            // local node 0..31
    int oc = tid & 7;             // batch pair 0..7
    int n  = n0 + ln;
    int r0 = rows[ln] - seg0;
    int r1 = ((ln == 31) ? rows[32] : rows[ln + 1]) - seg0;

    float a0 = 0.f, a1 = 0.f;
    const unsigned short* xq = xbc + (oc << 1);

    if (lds_ok) {
        for (int i = r0; i < r1; i += 8) {
            unsigned mm[8];
            unsigned rv[8];
            #pragma unroll
            for (int j = 0; j < 8; ++j) mm[j] = meta[i + j];
            #pragma unroll
            for (int j = 0; j < 8; ++j)
                rv[j] = *(const unsigned*)(xq + ((size_t)(mm[j] & 0xFFFFu) << 4));
            #pragma unroll
            for (int j = 0; j < 8; ++j) {
                float w = __uint_as_float(mm[j] & 0xFFFF0000u);
                a0 = fmaf(w, __uint_as_float(rv[j] << 16), a0);
                a1 = fmaf(w, __uint_as_float(rv[j] & 0xFFFF0000u), a1);
            }
        }
    } else {
        for (int i = r0; i < r1; i += 8) {
            unsigned mm[8];
            unsigned rv[8];
            #pragma unroll
            for (int j = 0; j < 8; ++j) mm[j] = csr2[seg0 + i + j];
            #pragma unroll
            for (int j = 0; j < 8; ++j)
                rv[j] = *(const unsigned*)(xq + ((size_t)(mm[j] & 0xFFFFu) << 4));
            #pragma unroll
            for (int j = 0; j < 8; ++j) {
                float w = __uint_as_float(mm[j] & 0xFFFF0000u);
                a0 = fmaf(w, __uint_as_float(rv[j] << 16), a0);
                a1 = fmaf(w, __uint_as_float(rv[j] & 0xFFFF0000u), a1);
            }
        }
    }

    float dt = dt_p[0];
    size_t own = ((size_t)n << 4) + (oc << 1);
    float2 xo = *(const float2*)(xf + own);
    xo.x = fmaf(dt, a0, xo.x);
    xo.y = fmaf(dt, a1, xo.y);
    *(float2*)(xf + own) = xo;

    unsigned pk = ((unsigned)f2bf(xo.x)) | (((unsigned)f2bf(xo.y)) << 16);
    *(unsigned*)(xbn + own) = pk;

    // LDS transpose: 32 nodes x 16 batches -> coalesced out writes
    int c0 = oc << 1;
    tile[ln][c0 + 0] = xo.x;
    tile[ln][c0 + 1] = xo.y;
    __syncthreads();
    int wb = tid >> 4;                // batch 0..15
    int wn = (tid & 15) << 1;         // local node 0,2,..,30
    float2 ov;
    ov.x = tile[wn + 0][wb];
    ov.y = tile[wn + 1][wb];
    *(float2*)(out + (size_t)wb * TN + (size_t)tstep * NODES_C + n0 + wn) = ov;
}

// ---------------------------------------------------------------------------
extern "C" void kernel_launch(void* const* d_in, const int* in_sizes, int n_in,
                              void* d_out, int out_size, void* d_ws, size_t ws_size,
                              hipStream_t stream)
{
    const float* x_in   = (const float*)d_in[0];
    // d_in[1] = points (unused by the reference computation)
    const int*   eidx   = (const int*)d_in[2];
    const float* dt_p   = (const float*)d_in[3];
    // d_in[4] = num_blocks (T derived from out_size instead)
    const float* dist   = (const float*)d_in[5];
    const float* coeffs = (const float*)d_in[6];

    const int* src = eidx;          // edge_index[0]
    const int* dst = eidx + E_C;    // edge_index[1]
    float* out = (float*)d_out;

    // workspace layout (~25 MB)
    char* ws = (char*)d_ws;
    int*      row_start = (int*)(ws + 0);                  // 256 KB
    int*      row_end   = (int*)(ws + (256u << 10));       // 256 KB
    int*      hist256   = (int*)(ws + (512u << 10));       // 1 KB
    int*      base256   = (int*)(ws + (516u << 10));       // 1 KB
    int*      fill256   = (int*)(ws + (520u << 10));       // 1 KB
    u64*      csr       = (u64*)(ws + (1u  << 20));        // 8 MB (raw bucketed)
    unsigned* csr2      = (unsigned*)(ws + (9u << 20));    // 8 MB (padded u32)
    float*    xf        = (float*)(ws + (17u << 20));      // 4 MB f32 state
    unsigned short* xb0 = (unsigned short*)(ws + (21u << 20)); // 2 MB mirror
    unsigned short* xb1 = (unsigned short*)(ws + (23u << 20)); // 2 MB mirror

    int T = out_size / (B_C * NODES_C);          // = 20
    size_t TN = (size_t)T * NODES_C;

    hipMemsetAsync(hist256, 0, 256 * sizeof(int), stream);
    k_hist   <<<E_C / 1024, 256, 0, stream>>>(dst, hist256);
    k_scan256<<<1, 256, 0, stream>>>(hist256, base256, fill256);
    k_bucket <<<E_C / 4096, 256, 0, stream>>>(src, dst, dist, coeffs, fill256, csr);
    k_sortb  <<<256, 256, 0, stream>>>(base256, hist256, csr, csr2, row_start, row_end);
    k_init   <<<(NODES_C * B_C) / 256, 256, 0, stream>>>(x_in, xf, xb0);

    unsigned short* xbufs[2] = { xb0, xb1 };
    for (int t = 0; t < T; ++t) {
        k_step<<<NODES_C / 32, 256, 0, stream>>>(
            row_start, row_end, csr2, xf,
            xbufs[t & 1], xbufs[(t + 1) & 1],
            out, dt_p, TN, t);
    }
}

// Round 13
// 242.050 us; speedup vs baseline: 19.0695x; 1.1616x over previous
//
#include <hip/hip_runtime.h>

// Problem constants (fixed by the reference file)
#define NODES_C 65536   // N*N, N=256
#define B_C     16
#define E_C     1048576 // NODES*16
#define K_C     5

#define MAXE    1024    // LDS padded-segment cap per 32-node step block (avg ~640)
#define CAP_RAW 6144    // fixed raw-bucket capacity (len~Poisson(4096), 32 sigma)
#define CAP_D   8192    // fixed padded stride per 256-node bucket (avg padded ~5000)

typedef unsigned long long u64;

__device__ inline unsigned short f2bf(float f) {   // RNE float->bf16
    unsigned u = __float_as_uint(f);
    u += 0x7FFFu + ((u >> 16) & 1u);
    return (unsigned short)(u >> 16);
}

// ---------------------------------------------------------------------------
// Tiny kernel: init per-bucket cursors to their fixed region bases
__global__ __launch_bounds__(256) void k_cinit(int* __restrict__ cursor)
{
    cursor[threadIdx.x] = threadIdx.x * CAP_RAW;
}

// ---------------------------------------------------------------------------
// Build kernel C: compute w, pack u64 {w_f32 | dst&255 | src16}, bucket by
// dst>>8 into fixed-capacity raw regions via atomic cursors (order within a
// bucket irrelevant). 256 blocks x 4096 edges. No pre-count pass needed.
__global__ __launch_bounds__(256) void k_bucket(
    const int* __restrict__ src, const int* __restrict__ dst,
    const float* __restrict__ dist, const float* __restrict__ coeffs,
    int* __restrict__ cursor, u64* __restrict__ craw)
{
    __shared__ int hist[256];
    __shared__ int scan[256];
    __shared__ int exs[256];
    __shared__ int gpos[256];
    __shared__ int lfill[256];
    __shared__ u64 stage[4096];

    int tid = threadIdx.x;
    hist[tid] = 0;
    __syncthreads();

    float c0 = coeffs[0], c1 = coeffs[1], c2 = coeffs[2], c3 = coeffs[3], c4 = coeffs[4];
    int e0 = blockIdx.x * 4096;
    u64 pk[16];
    int bk[16];
    #pragma unroll
    for (int j = 0; j < 16; ++j) {
        int e = e0 + j * 256 + tid;
        unsigned s = (unsigned)src[e];
        unsigned d = (unsigned)dst[e];
        const float* dd = dist + (size_t)e * K_C;
        float wv = dd[0]*c0 + dd[1]*c1 + dd[2]*c2 + dd[3]*c3 + dd[4]*c4;
        pk[j] = ((u64)__float_as_uint(wv) << 32) | ((d & 255u) << 16) | s;
        bk[j] = (int)(d >> 8);
        atomicAdd(&hist[bk[j]], 1);
    }
    __syncthreads();

    scan[tid] = hist[tid];
    __syncthreads();
    for (int off = 1; off < 256; off <<= 1) {
        int v = scan[tid];
        int a = (tid >= off) ? scan[tid - off] : 0;
        __syncthreads();
        scan[tid] = v + a;
        __syncthreads();
    }
    exs[tid]   = scan[tid] - hist[tid];               // local exclusive base
    gpos[tid]  = atomicAdd(&cursor[tid], hist[tid]);  // absolute run start
    lfill[tid] = 0;
    __syncthreads();

    #pragma unroll
    for (int j = 0; j < 16; ++j) {
        int b = bk[j];
        int p = exs[b] + atomicAdd(&lfill[b], 1);
        stage[p] = pk[j];
    }
    __syncthreads();

    int c = hist[tid], g = gpos[tid], lb = exs[tid];
    for (int i = 0; i < c; ++i) craw[g + i] = stage[lb + i];
}

// ---------------------------------------------------------------------------
// Build kernel D: one block per bucket. Counting-sort by dst&255 with rows
// PADDED to multiples of 8 (zero entries: w=0, src=0), emitted as u32
// {bf16 w | u16 src} at the bucket's FIXED base B0 = b*CAP_D.
// Emits row_start AND row_end (row_end avoids swallowing the pad-tail gap).
__global__ __launch_bounds__(256) void k_sortb(
    const int* __restrict__ cursor, const u64* __restrict__ craw,
    unsigned* __restrict__ csr2, int* __restrict__ row_start,
    int* __restrict__ row_end)
{
    __shared__ unsigned stage[CAP_D];
    __shared__ int h[256];
    __shared__ int sc[256];
    __shared__ int ex[256];
    __shared__ int lf[256];

    int b = blockIdx.x, tid = threadIdx.x;
    int b0 = b * CAP_RAW;
    int len = cursor[b] - b0;
    int B0 = b * CAP_D;

    h[tid] = 0;
    for (int i = tid; i < CAP_D; i += 256) stage[i] = 0;   // pad entries
    __syncthreads();
    for (int i = tid; i < len; i += 256)
        atomicAdd(&h[(int)((craw[b0 + i] >> 16) & 255u)], 1);
    __syncthreads();

    int hp = (h[tid] + 7) & ~7;              // padded row length
    sc[tid] = hp;
    __syncthreads();
    for (int off = 1; off < 256; off <<= 1) {
        int v = sc[tid];
        int a = (tid >= off) ? sc[tid - off] : 0;
        __syncthreads();
        sc[tid] = v + a;
        __syncthreads();
    }
    ex[tid] = sc[tid] - hp;                  // padded exclusive base
    row_start[b * 256 + tid] = B0 + ex[tid];
    row_end  [b * 256 + tid] = B0 + ex[tid] + hp;
    lf[tid] = 0;
    __syncthreads();

    for (int i = tid; i < len; i += 256) {
        u64 m = craw[b0 + i];
        int dl = (int)((m >> 16) & 255u);
        int p = ex[dl] + atomicAdd(&lf[dl], 1);
        unsigned wbf = ((unsigned)f2bf(__uint_as_float((unsigned)(m >> 32)))) << 16;
        stage[p] = wbf | (unsigned)(m & 0xFFFFu);
    }
    __syncthreads();
    int plen = sc[255];
    for (int i = tid; i < plen; i += 256) csr2[B0 + i] = stage[i];
}

// ---------------------------------------------------------------------------
// Kernel: init node-major f32 state + full bf16 mirror [n][16]
// (runs AFTER k_sortb: xf/mirror alias the then-dead raw bucket region)
__global__ __launch_bounds__(256) void k_init(
    const float* __restrict__ x_in, float* __restrict__ xf,
    unsigned short* __restrict__ xb)
{
    int tid = blockIdx.x * 256 + threadIdx.x;   // tid = b*N + n
    int b = tid >> 16;
    int n = tid & 0xFFFF;
    float v = x_in[tid];
    xf[((size_t)n << 4) + b] = v;
    xb[((size_t)n << 4) + b] = f2bf(v);
}

// ---------------------------------------------------------------------------
// Step kernel: 32-node blocks, 8 lanes/node (batch pair each -> one 32B
// request per edge), 2048 blocks = 32 waves/CU. Rows padded to x8.
// NT stores on all streaming writes (out/xf/mirror) keep L2 mirror-resident.
__global__ __launch_bounds__(256, 8) void k_step(
    const int* __restrict__ row_start, const int* __restrict__ row_end,
    const unsigned* __restrict__ csr2, float* __restrict__ xf,
    const unsigned short* __restrict__ xbc, unsigned short* __restrict__ xbn,
    float* __restrict__ out, const float* __restrict__ dt_p,
    size_t TN, int tstep)
{
    __shared__ unsigned meta[MAXE];
    __shared__ int rows[33];
    __shared__ float tile[32][17];

    int tid = threadIdx.x;
    int n0  = blockIdx.x * 32;

    if (tid < 32) rows[tid] = row_start[n0 + tid];
    if (tid == 32) rows[32] = row_end[n0 + 31];
    __syncthreads();
    int seg0   = rows[0];
    int segLen = rows[32] - seg0;
    bool lds_ok = (segLen <= MAXE);
    if (lds_ok)
        for (int i = tid; i < segLen; i += 256) meta[i] = csr2[seg0 + i];
    __syncthreads();

    int ln = tid >> 3;            // local node 0..31
    int oc = tid & 7;             // batch pair 0..7
    int n  = n0 + ln;
    int r0 = rows[ln] - seg0;
    int r1 = ((ln == 31) ? rows[32] : rows[ln + 1]) - seg0;

    float a0 = 0.f, a1 = 0.f;
    const unsigned short* xq = xbc + (oc << 1);

    if (lds_ok) {
        for (int i = r0; i < r1; i += 8) {
            unsigned mm[8];
            unsigned rv[8];
            #pragma unroll
            for (int j = 0; j < 8; ++j) mm[j] = meta[i + j];
            #pragma unroll
            for (int j = 0; j < 8; ++j)
                rv[j] = *(const unsigned*)(xq + ((size_t)(mm[j] & 0xFFFFu) << 4));
            #pragma unroll
            for (int j = 0; j < 8; ++j) {
                float w = __uint_as_float(mm[j] & 0xFFFF0000u);
                a0 = fmaf(w, __uint_as_float(rv[j] << 16), a0);
                a1 = fmaf(w, __uint_as_float(rv[j] & 0xFFFF0000u), a1);
            }
        }
    } else {
        for (int i = r0; i < r1; i += 8) {
            unsigned mm[8];
            unsigned rv[8];
            #pragma unroll
            for (int j = 0; j < 8; ++j) mm[j] = csr2[seg0 + i + j];
            #pragma unroll
            for (int j = 0; j < 8; ++j)
                rv[j] = *(const unsigned*)(xq + ((size_t)(mm[j] & 0xFFFFu) << 4));
            #pragma unroll
            for (int j = 0; j < 8; ++j) {
                float w = __uint_as_float(mm[j] & 0xFFFF0000u);
                a0 = fmaf(w, __uint_as_float(rv[j] << 16), a0);
                a1 = fmaf(w, __uint_as_float(rv[j] & 0xFFFF0000u), a1);
            }
        }
    }

    float dt = dt_p[0];
    size_t own = ((size_t)n << 4) + (oc << 1);
    float2 xo = *(const float2*)(xf + own);
    xo.x = fmaf(dt, a0, xo.x);
    xo.y = fmaf(dt, a1, xo.y);
    __builtin_nontemporal_store(*(const double*)&xo, (double*)(xf + own));

    unsigned pk = ((unsigned)f2bf(xo.x)) | (((unsigned)f2bf(xo.y)) << 16);
    __builtin_nontemporal_store(pk, (unsigned*)(xbn + own));

    // LDS transpose: 32 nodes x 16 batches -> coalesced NT out writes
    int c0 = oc << 1;
    tile[ln][c0 + 0] = xo.x;
    tile[ln][c0 + 1] = xo.y;
    __syncthreads();
    int wb = tid >> 4;                // batch 0..15
    int wn = (tid & 15) << 1;         // local node 0,2,..,30
    float2 ov;
    ov.x = tile[wn + 0][wb];
    ov.y = tile[wn + 1][wb];
    __builtin_nontemporal_store(*(const double*)&ov,
        (double*)(out + (size_t)wb * TN + (size_t)tstep * NODES_C + n0 + wn));
}

// ---------------------------------------------------------------------------
extern "C" void kernel_launch(void* const* d_in, const int* in_sizes, int n_in,
                              void* d_out, int out_size, void* d_ws, size_t ws_size,
                              hipStream_t stream)
{
    const float* x_in   = (const float*)d_in[0];
    // d_in[1] = points (unused by the reference computation)
    const int*   eidx   = (const int*)d_in[2];
    const float* dt_p   = (const float*)d_in[3];
    // d_in[4] = num_blocks (T derived from out_size instead)
    const float* dist   = (const float*)d_in[5];
    const float* coeffs = (const float*)d_in[6];

    const int* src = eidx;          // edge_index[0]
    const int* dst = eidx + E_C;    // edge_index[1]
    float* out = (float*)d_out;

    // workspace layout (~22 MB); xf/mirrors alias the raw-bucket region,
    // which is dead after k_sortb (k_init runs after it, stream-ordered).
    char* ws = (char*)d_ws;
    u64*      craw      = (u64*)(ws + 0);                  // 12.6 MB (dead after k_sortb)
    float*    xf        = (float*)(ws + 0);                // 4 MB  (alias, from k_init)
    unsigned short* xb0 = (unsigned short*)(ws + (4u << 20));  // 2 MB (alias)
    unsigned short* xb1 = (unsigned short*)(ws + (6u << 20));  // 2 MB (alias)
    unsigned* csr2      = (unsigned*)(ws + (13u << 20));   // 8 MB
    int*      row_start = (int*)(ws + (21u << 20));            // 256 KB
    int*      row_end   = (int*)(ws + (21u << 20) + (256u << 10)); // 256 KB
    int*      cursor    = (int*)(ws + (21u << 20) + (512u << 10)); // 1 KB

    int T = out_size / (B_C * NODES_C);          // = 20
    size_t TN = (size_t)T * NODES_C;

    k_cinit <<<1, 256, 0, stream>>>(cursor);
    k_bucket<<<E_C / 4096, 256, 0, stream>>>(src, dst, dist, coeffs, cursor, craw);
    k_sortb <<<256, 256, 0, stream>>>(cursor, craw, csr2, row_start, row_end);
    k_init  <<<(NODES_C * B_C) / 256, 256, 0, stream>>>(x_in, xf, xb0);

    unsigned short* xbufs[2] = { xb0, xb1 };
    for (int t = 0; t < T; ++t) {
        k_step<<<NODES_C / 32, 256, 0, stream>>>(
            row_start, row_end, csr2, xf,
            xbufs[t & 1], xbufs[(t + 1) & 1],
            out, dt_p, TN, t);
    }
}